// Round 9
// baseline (305.093 us; speedup 1.0000x reference)
//
#include <hip/hip_runtime.h>

#define NS_MAX 2048
#define ES_MAX 16384
#define ELDS 4096
#define LN_EPS 1e-5f
#define NBLK 256
#define NTHR 512
#define SLOTS 4          // NTHR/128
#define BMP_MAX 3328     // words -> N <= 106496 in LDS

// bar words (64B apart): [0]=arrive, [16]=gen, [32]=done-ticket, [48]=node cnt, [49]=edge cnt
struct GnnParams {
  const float* x; const int* src; const int* dst; const int* curp;
  const float* W1; const float* b1; const float* g1; const float* be1;
  const float* W2; const float* b2; const float* g2; const float* be2;
  const float* W3; const float* b3; const float* g3; const float* be3;
  int* bar; unsigned* B1; unsigned* B2; int* deg;      // zeroed by host memset
  int* nodelist; int* lidx; int* esrc; int* edst; int2* e2;
  float* HA; float* HB; float* H3; float* X3;
  float* out;
  int N; int E;
};

__device__ __forceinline__ void gbar(int* bar){
  __syncthreads();
  if (threadIdx.x == 0){
    int g = __hip_atomic_load(&bar[16], __ATOMIC_RELAXED, __HIP_MEMORY_SCOPE_AGENT);
    int a = __hip_atomic_fetch_add(&bar[0], 1, __ATOMIC_ACQ_REL, __HIP_MEMORY_SCOPE_AGENT);
    if (a == NBLK-1){
      __hip_atomic_store(&bar[0], 0, __ATOMIC_RELAXED, __HIP_MEMORY_SCOPE_AGENT);
      __hip_atomic_fetch_add(&bar[16], 1, __ATOMIC_ACQ_REL, __HIP_MEMORY_SCOPE_AGENT);
    } else {
      while (__hip_atomic_load(&bar[16], __ATOMIC_RELAXED, __HIP_MEMORY_SCOPE_AGENT) == g)
        __builtin_amdgcn_s_sleep(2);
      __builtin_amdgcn_fence(__ATOMIC_ACQUIRE, "agent");
    }
  }
  __syncthreads();
}

__global__ __launch_bounds__(NTHR) void fused_gnn(GnnParams p){
  const int tid  = threadIdx.x;
  const int gt   = blockIdx.x*NTHR + tid;
  const int gs   = NBLK*NTHR;
  const int slot = tid >> 7;     // 128-thread slot (0..3)
  const int d    = tid & 127;
  const int s8   = tid >> 6;     // 64-thread slot (0..7)
  const int t64  = tid & 63;
  const int cur  = p.curp[0];
  const int NW   = (p.N + 31) >> 5;
  const bool fits = (NW <= BMP_MAX);

  __shared__ unsigned bmp[BMP_MAX];     // 13 KB (P2/P3 only)
  __shared__ int2  eL[ELDS];            // 32 KB (staged P5, persists)
  __shared__ float disL[NS_MAX];        // 8 KB  (staged P5, persists)
  __shared__ float rows[SLOTS][128];    // 2 KB
  __shared__ float redm[SLOTS][2];
  __shared__ float redv[SLOTS][2];
  __shared__ float redp[NTHR/64][64];   // 2 KB
  __shared__ int lastflag;

  auto subsum128 = [&](float s, float (*red)[2]) -> float {
    #pragma unroll
    for (int o = 32; o >= 1; o >>= 1) s += __shfl_xor(s, o);
    if ((tid & 63) == 0) red[slot][(tid >> 6) & 1] = s;
    __syncthreads();
    return red[slot][0] + red[slot][1];
  };
  auto ln128 = [&](float v, float gd, float bed) -> float {
    float tot = subsum128(v, redm);
    float mu  = tot * (1.0f/128.0f);
    float dv  = v - mu;
    float tot2 = subsum128(dv*dv, redv);
    float var = tot2 * (1.0f/128.0f);
    return dv * rsqrtf(var + LN_EPS) * gd + bed;
  };

  const int nv = p.E >> 2;
  const int4* d4 = (const int4*)p.dst;

  // ================= P1: hop 1 (dst == cur -> B1 |= src), seed cur ========
  if (gt == 0) atomicOr(&p.B1[cur >> 5], 1u << (cur & 31));
  {
    auto proc = [&](int4 dd, int b){
      if (dd.x == cur){ int s = p.src[b+0]; atomicOr(&p.B1[s>>5], 1u<<(s&31)); }
      if (dd.y == cur){ int s = p.src[b+1]; atomicOr(&p.B1[s>>5], 1u<<(s&31)); }
      if (dd.z == cur){ int s = p.src[b+2]; atomicOr(&p.B1[s>>5], 1u<<(s&31)); }
      if (dd.w == cur){ int s = p.src[b+3]; atomicOr(&p.B1[s>>5], 1u<<(s&31)); }
    };
    for (int v0 = gt; v0 < nv; v0 += 4*gs){
      int v1 = v0+gs, v2 = v0+2*gs, v3 = v0+3*gs;
      bool c1 = v1 < nv, c2 = v2 < nv, c3 = v3 < nv;
      int4 a0 = d4[v0], a1, a2, a3;
      if (c1) a1 = d4[v1];
      if (c2) a2 = d4[v2];
      if (c3) a3 = d4[v3];
      proc(a0, v0<<2);
      if (c1) proc(a1, v1<<2);
      if (c2) proc(a2, v2<<2);
      if (c3) proc(a3, v3<<2);
    }
    for (int e = (nv<<2) + gt; e < p.E; e += gs)
      if (p.dst[e] == cur){ int s = p.src[e]; atomicOr(&p.B1[s>>5], 1u<<(s&31)); }
  }
  gbar(p.bar);

  // ================= P2: hop 2 (B1[dst] -> B2 |= src) =====================
  {
    if (fits){
      for (int w = tid; w < NW; w += NTHR) bmp[w] = p.B1[w];
    }
    __syncthreads();
    auto test1 = [&](int v)->bool{
      return fits ? ((bmp[v>>5] >> (v&31)) & 1u)
                  : ((p.B1[v>>5] >> (v&31)) & 1u);
    };
    auto proc = [&](int4 dd, int b){
      if (test1(dd.x)){ int s = p.src[b+0]; atomicOr(&p.B2[s>>5], 1u<<(s&31)); }
      if (test1(dd.y)){ int s = p.src[b+1]; atomicOr(&p.B2[s>>5], 1u<<(s&31)); }
      if (test1(dd.z)){ int s = p.src[b+2]; atomicOr(&p.B2[s>>5], 1u<<(s&31)); }
      if (test1(dd.w)){ int s = p.src[b+3]; atomicOr(&p.B2[s>>5], 1u<<(s&31)); }
    };
    for (int v0 = gt; v0 < nv; v0 += 4*gs){
      int v1 = v0+gs, v2 = v0+2*gs, v3 = v0+3*gs;
      bool c1 = v1 < nv, c2 = v2 < nv, c3 = v3 < nv;
      int4 a0 = d4[v0], a1, a2, a3;
      if (c1) a1 = d4[v1];
      if (c2) a2 = d4[v2];
      if (c3) a3 = d4[v3];
      proc(a0, v0<<2);
      if (c1) proc(a1, v1<<2);
      if (c2) proc(a2, v2<<2);
      if (c3) proc(a3, v3<<2);
    }
    for (int e = (nv<<2) + gt; e < p.E; e += gs){
      int dd = p.dst[e];
      if (test1(dd)){ int s = p.src[e]; atomicOr(&p.B2[s>>5], 1u<<(s&31)); }
    }
  }
  gbar(p.bar);

  // ================= P3: F = B1|B2: edge compact + node compact ===========
  {
    if (fits){
      for (int w = tid; w < NW; w += NTHR) bmp[w] = p.B1[w] | p.B2[w];
    }
    __syncthreads();
    auto testF = [&](int v)->bool{
      return fits ? ((bmp[v>>5] >> (v&31)) & 1u)
                  : (((p.B1[v>>5] | p.B2[v>>5]) >> (v&31)) & 1u);
    };
    auto proc = [&](int dd, int b){
      if (testF(dd)){
        int s = p.src[b];
        if (testF(s)){
          int idx = atomicAdd(&p.bar[49], 1);
          if (idx < ES_MAX){ p.esrc[idx] = s; p.edst[idx] = dd; }
        }
      }
    };
    for (int v0 = gt; v0 < nv; v0 += 4*gs){
      int v1 = v0+gs, v2 = v0+2*gs, v3 = v0+3*gs;
      bool c1 = v1 < nv, c2 = v2 < nv, c3 = v3 < nv;
      int4 a0 = d4[v0], a1, a2, a3;
      if (c1) a1 = d4[v1];
      if (c2) a2 = d4[v2];
      if (c3) a3 = d4[v3];
      proc(a0.x, (v0<<2)+0); proc(a0.y, (v0<<2)+1); proc(a0.z, (v0<<2)+2); proc(a0.w, (v0<<2)+3);
      if (c1){ proc(a1.x, (v1<<2)+0); proc(a1.y, (v1<<2)+1); proc(a1.z, (v1<<2)+2); proc(a1.w, (v1<<2)+3); }
      if (c2){ proc(a2.x, (v2<<2)+0); proc(a2.y, (v2<<2)+1); proc(a2.z, (v2<<2)+2); proc(a2.w, (v2<<2)+3); }
      if (c3){ proc(a3.x, (v3<<2)+0); proc(a3.y, (v3<<2)+1); proc(a3.z, (v3<<2)+2); proc(a3.w, (v3<<2)+3); }
    }
    for (int e = (nv<<2) + gt; e < p.E; e += gs) proc(p.dst[e], e);
    // node compaction from bitmap words
    for (int w = gt; w < NW; w += gs){
      unsigned m = fits ? bmp[w] : (p.B1[w] | p.B2[w]);
      int c = __popc(m);
      if (c){
        int base = atomicAdd(&p.bar[48], c);
        int j = 0;
        while (m){
          int b = __ffs(m) - 1; m &= m - 1;
          int l = base + j; ++j;
          int v = (w << 5) | b;
          if (l < NS_MAX){ p.nodelist[l] = v; p.lidx[v] = l; }
        }
      }
    }
  }
  gbar(p.bar);

  const int ncnt = min(__hip_atomic_load(&p.bar[48], __ATOMIC_RELAXED, __HIP_MEMORY_SCOPE_AGENT), NS_MAX);
  const int ec   = min(__hip_atomic_load(&p.bar[49], __ATOMIC_RELAXED, __HIP_MEMORY_SCOPE_AGENT), ES_MAX);

  // ================= P4: localize edges + deg + gemm1 (x @ W1 -> HA) ======
  for (int i = gt; i < ec; i += gs){
    int ls = p.lidx[p.esrc[i]], ld = p.lidx[p.edst[i]];
    if ((unsigned)ls < NS_MAX && (unsigned)ld < NS_MAX){
      p.e2[i] = make_int2(ls, ld);
      atomicAdd(&p.deg[ld], 1);
    } else { p.e2[i] = make_int2(0, -1); }
  }
  for (int base = blockIdx.x*SLOTS; base < ncnt; base += NBLK*SLOTS){
    int l = base + slot; bool act = (l < ncnt);
    float xv = 0.0f;
    if (act){ int v = p.nodelist[l]; xv = p.x[(size_t)v*128 + d]; }
    rows[slot][d] = xv;
    __syncthreads();
    float acc = 0.0f;
    #pragma unroll 8
    for (int k = 0; k < 128; ++k) acc = fmaf(rows[slot][k], p.W1[k*128 + d], acc);
    if (act) p.HA[l*128 + d] = acc;
    __syncthreads();
  }
  gbar(p.bar);

  // ================= stage edges + dis into LDS (persist to end) ==========
  const bool eFit = (ec <= ELDS);
  for (int i = tid; i < ec && i < ELDS; i += NTHR) eL[i] = p.e2[i];
  for (int j = tid; j < ncnt; j += NTHR) disL[j] = rsqrtf((float)(p.deg[j] + 1));
  __syncthreads();

  // ================= P5: gather(HA)+ln1+gemm2 -> HB =======================
  for (int base = blockIdx.x*SLOTS; base < ncnt; base += NBLK*SLOTS){
    int l = base + slot; bool act = (l < ncnt);
    float acc = 0.0f;
    if (act){
      float dl = disL[l];
      acc = p.HA[l*128 + d] * dl * dl;                 // self loop (1/deg)
      for (int i = 0; i < ec; ++i){
        int2 e = eFit ? eL[i] : p.e2[i];
        if (e.y == l) acc += disL[e.x] * dl * p.HA[e.x*128 + d];
      }
      acc += p.b1[d];
    }
    float v = fmaxf(acc, 0.0f);
    float y = ln128(v, p.g1[d], p.be1[d]);
    rows[slot][d] = y;
    __syncthreads();
    float acc2 = 0.0f;
    #pragma unroll 8
    for (int k = 0; k < 128; ++k) acc2 = fmaf(rows[slot][k], p.W2[k*128 + d], acc2);
    if (act) p.HB[l*128 + d] = acc2;
    __syncthreads();
  }
  gbar(p.bar);

  // ================= P6: gather(HB)+ln2+gemm3 -> H3 (64) ==================
  for (int base = blockIdx.x*SLOTS; base < ncnt; base += NBLK*SLOTS){
    int l = base + slot; bool act = (l < ncnt);
    float acc = 0.0f;
    if (act){
      float dl = disL[l];
      acc = p.HB[l*128 + d] * dl * dl;
      for (int i = 0; i < ec; ++i){
        int2 e = eFit ? eL[i] : p.e2[i];
        if (e.y == l) acc += disL[e.x] * dl * p.HB[e.x*128 + d];
      }
      acc += p.b2[d];
    }
    float v = fmaxf(acc, 0.0f);
    float y = ln128(v, p.g2[d], p.be2[d]);
    rows[slot][d] = y;
    __syncthreads();
    if (d < 64){
      float acc2 = 0.0f;
      #pragma unroll 8
      for (int k = 0; k < 128; ++k) acc2 = fmaf(rows[slot][k], p.W3[k*64 + d], acc2);
      if (act) p.H3[l*64 + d] = acc2;
    }
    __syncthreads();
  }
  gbar(p.bar);

  // ================= P7: gather(H3)+ln3 -> X3 (64-wide slots) =============
  for (int base = blockIdx.x*(NTHR/64); base < ncnt; base += NBLK*(NTHR/64)){
    int l = base + s8; bool act = (l < ncnt);
    float acc = 0.0f;
    if (act){
      float dl = disL[l];
      acc = p.H3[l*64 + t64] * dl * dl;
      for (int i = 0; i < ec; ++i){
        int2 e = eFit ? eL[i] : p.e2[i];
        if (e.y == l) acc += disL[e.x] * dl * p.H3[e.x*64 + t64];
      }
      acc += p.b3[t64];
    }
    float v = fmaxf(acc, 0.0f);
    float s = v;
    #pragma unroll
    for (int o = 32; o >= 1; o >>= 1) s += __shfl_xor(s, o);
    float mu = s * (1.0f/64.0f);
    float dv = v - mu;
    float s2 = dv*dv;
    #pragma unroll
    for (int o = 32; o >= 1; o >>= 1) s2 += __shfl_xor(s2, o);
    float var = s2 * (1.0f/64.0f);
    float y = dv * rsqrtf(var + LN_EPS) * p.g3[t64] + p.be3[t64];
    if (act) p.X3[l*64 + t64] = y;
  }
  __syncthreads();
  if (tid == 0){
    int t0 = __hip_atomic_fetch_add(&p.bar[32], 1, __ATOMIC_ACQ_REL, __HIP_MEMORY_SCOPE_AGENT);
    lastflag = (t0 == NBLK-1) ? 1 : 0;
  }
  __syncthreads();
  if (lastflag){
    __builtin_amdgcn_fence(__ATOMIC_ACQUIRE, "agent");
    float s = 0.0f;
    for (int l = s8; l < ncnt; l += NTHR/64) s += p.X3[l*64 + t64];
    redp[s8][t64] = s;
    __syncthreads();
    if (s8 == 0){
      float tot = 0.0f;
      #pragma unroll
      for (int k = 0; k < NTHR/64; ++k) tot += redp[k][t64];
      p.out[t64] = tot / (float)ncnt;
    }
  }
}

extern "C" void kernel_launch(void* const* d_in, const int* in_sizes, int n_in,
                              void* d_out, int out_size, void* d_ws, size_t ws_size,
                              hipStream_t stream) {
  const float* x    = (const float*)d_in[0];
  const int*   ei   = (const int*)d_in[1];
  const int*   curp = (const int*)d_in[2];

  int N = in_sizes[0] / 128;
  int E = in_sizes[1] / 2;
  int NW = (N + 31) / 32;
  int NWa = (NW + 63) & ~63;

  char* wp = (char*)d_ws;
  auto carve = [&](size_t bytes) -> void* {
    void* r = (void*)wp;
    wp += (bytes + 255) & ~(size_t)255;
    return r;
  };
  GnnParams p;
  p.x = x; p.src = ei; p.dst = ei + E; p.curp = curp;
  p.W1 = (const float*)d_in[3];  p.b1 = (const float*)d_in[4];
  p.g1 = (const float*)d_in[5];  p.be1= (const float*)d_in[6];
  p.W2 = (const float*)d_in[7];  p.b2 = (const float*)d_in[8];
  p.g2 = (const float*)d_in[9];  p.be2= (const float*)d_in[10];
  p.W3 = (const float*)d_in[11]; p.b3 = (const float*)d_in[12];
  p.g3 = (const float*)d_in[13]; p.be3= (const float*)d_in[14];

  // ---- zeroed head (one small memset) ----
  p.bar = (int*)     carve(256);
  p.B1  = (unsigned*)carve((size_t)NWa*4);
  p.B2  = (unsigned*)carve((size_t)NWa*4);
  p.deg = (int*)     carve(NS_MAX*4);
  size_t head_bytes = (size_t)(wp - (char*)d_ws);
  // ---- uninitialized tail ----
  p.nodelist = (int*)  carve(NS_MAX*4);
  p.lidx     = (int*)  carve((size_t)N*4);
  p.esrc     = (int*)  carve(ES_MAX*4);
  p.edst     = (int*)  carve(ES_MAX*4);
  p.e2       = (int2*) carve((size_t)ES_MAX*8);
  p.HA       = (float*)carve((size_t)NS_MAX*128*4);
  p.HB       = (float*)carve((size_t)NS_MAX*128*4);
  p.H3       = (float*)carve((size_t)NS_MAX*64*4);
  p.X3       = (float*)carve((size_t)NS_MAX*64*4);
  p.out      = (float*)d_out;
  p.N = N; p.E = E;
  (void)ws_size; (void)n_in; (void)out_size;

  hipMemsetAsync(d_ws, 0, head_bytes, stream);
  fused_gnn<<<dim3(NBLK), dim3(NTHR), 0, stream>>>(p);
}